// Round 1
// 1118.341 us; speedup vs baseline: 1.0367x; 1.0367x over previous
//
#include <hip/hip_runtime.h>

#define BATCH 32
#define PIX   3072
#define NEU   4096
#define STEPS 99           // reference runs NUM_STEPS-1 = 99 update iterations
#define ETA   (0.001f / 0.03f)
#define NBLK  128
#define TPB   512
#define SLOT  (BATCH * NEU)          // halves per rotating a-buffer (256 KB)

typedef __bf16 bf16x8 __attribute__((ext_vector_type(8)));
typedef float  f32x4  __attribute__((ext_vector_type(4)));

__device__ __forceinline__ float softt(float u, float lam) {
    return u > lam ? u - lam : (u < -lam ? u + lam : 0.0f);
}

// fp32 -> bf16 round-to-nearest-even
__device__ __forceinline__ unsigned short f2b(float f) {
    unsigned int u = __builtin_bit_cast(unsigned int, f);
    u = (u + 0x7FFFu + ((u >> 16) & 1u)) >> 16;
    return (unsigned short)u;
}

__device__ __forceinline__ bf16x8 ldfrag_g(const unsigned short* p) {
    uint4 v = *(const uint4*)p;
    return __builtin_bit_cast(bf16x8, v);
}

// ---------------------------------------------------------------------------
// φ (fp32 [PIX][NEU]) -> φT (bf16 [NEU][PIX]).  64x64 tiles via LDS.
__global__ void transp(const float* __restrict__ phi, unsigned short* __restrict__ phiT) {
    __shared__ float t[64][65];
    const int n0 = blockIdx.x * 64, p0 = blockIdx.y * 64;
    const int tid = threadIdx.x;
    #pragma unroll
    for (int pass = 0; pass < 4; ++pass) {
        const int r  = pass * 16 + (tid >> 4);
        const int c4 = (tid & 15) * 4;
        float4 v = *(const float4*)(phi + (size_t)(p0 + r) * NEU + n0 + c4);
        t[r][c4 + 0] = v.x; t[r][c4 + 1] = v.y; t[r][c4 + 2] = v.z; t[r][c4 + 3] = v.w;
    }
    __syncthreads();
    #pragma unroll
    for (int pass = 0; pass < 2; ++pass) {
        const int cp = pass * 32 + (tid >> 3);
        const int p8 = (tid & 7) * 8;
        unsigned int w0 = (unsigned int)f2b(t[p8 + 0][cp]) | ((unsigned int)f2b(t[p8 + 1][cp]) << 16);
        unsigned int w1 = (unsigned int)f2b(t[p8 + 2][cp]) | ((unsigned int)f2b(t[p8 + 3][cp]) << 16);
        unsigned int w2 = (unsigned int)f2b(t[p8 + 4][cp]) | ((unsigned int)f2b(t[p8 + 5][cp]) << 16);
        unsigned int w3 = (unsigned int)f2b(t[p8 + 6][cp]) | ((unsigned int)f2b(t[p8 + 7][cp]) << 16);
        uint4 o = make_uint4(w0, w1, w2, w3);
        *(uint4*)(phiT + (size_t)(n0 + cp) * PIX + p0 + p8) = o;
    }
}

// ---------------------------------------------------------------------------
// G = φᵀφ (symmetric, bf16). Upper-triangle blocks only; mirror-store.
__global__ void gemm_G(const unsigned short* __restrict__ phiT, unsigned short* __restrict__ G) {
    if (blockIdx.y > blockIdx.x) return;
    __shared__ __align__(16) unsigned short lds[2][128 * 40];
    const int m0 = blockIdx.y * 128, n0 = blockIdx.x * 128;
    const int tid  = threadIdx.x;
    const int lane = tid & 63, w = tid >> 6;
    const int wm = (w & 1) * 64, wn = (w >> 1) * 64;
    const int q8 = (lane >> 4) * 8, l15 = lane & 15;
    f32x4 acc[4][4] = {};
    for (int k0 = 0; k0 < PIX; k0 += 32) {
        __syncthreads();
        #pragma unroll
        for (int it = 0; it < 2; ++it) {
            const int id = tid + 256 * it;
            const int row = id >> 2, q = id & 3;
            uint4 va = *(const uint4*)(phiT + (size_t)(m0 + row) * PIX + k0 + q * 8);
            *(uint4*)(&lds[0][row * 40 + q * 8]) = va;
            uint4 vb = *(const uint4*)(phiT + (size_t)(n0 + row) * PIX + k0 + q * 8);
            *(uint4*)(&lds[1][row * 40 + q * 8]) = vb;
        }
        __syncthreads();
        bf16x8 af[4], bfr[4];
        #pragma unroll
        for (int i = 0; i < 4; ++i) {
            af[i]  = *(const bf16x8*)(&lds[0][(wm + i * 16 + l15) * 40 + q8]);
            bfr[i] = *(const bf16x8*)(&lds[1][(wn + i * 16 + l15) * 40 + q8]);
        }
        #pragma unroll
        for (int i = 0; i < 4; ++i)
            #pragma unroll
            for (int j = 0; j < 4; ++j)
                acc[i][j] = __builtin_amdgcn_mfma_f32_16x16x32_bf16(af[i], bfr[j], acc[i][j], 0, 0, 0);
    }
    const int q = lane >> 4;
    const bool offdiag = (blockIdx.y != blockIdx.x);
    #pragma unroll
    for (int i = 0; i < 4; ++i)
        #pragma unroll
        for (int j = 0; j < 4; ++j) {
            unsigned short pk[4];
            #pragma unroll
            for (int r = 0; r < 4; ++r) {
                const int gm = m0 + wm + i * 16 + q * 4 + r;
                const int gn = n0 + wn + j * 16 + l15;
                const unsigned short v = f2b(acc[i][j][r]);
                G[(size_t)gm * NEU + gn] = v;
                pk[r] = v;
            }
            if (offdiag) {
                const int gm0 = m0 + wm + i * 16 + q * 4;
                const int gn  = n0 + wn + j * 16 + l15;
                *(ushort4*)(G + (size_t)gn * NEU + gm0) = make_ushort4(pk[0], pk[1], pk[2], pk[3]);
            }
        }
}

// ---------------------------------------------------------------------------
// b = x @ phi; zero the 128 producer flags (64-B padded).
// grid 256 (16-col strips), block 512
__global__ void lca_binit(const float* __restrict__ x, const unsigned short* __restrict__ phiT,
                          float* __restrict__ b, unsigned int* __restrict__ arr) {
    __shared__ float red[8 * 512];
    const int tid = threadIdx.x;
    const int lane = tid & 63, w = tid >> 6;
    const int n0 = blockIdx.x * 16;
    const int kbase = w * (PIX / 8);
    const int q8 = (lane >> 4) * 8, l15 = lane & 15;
    if (blockIdx.x < NBLK && tid < 16) arr[blockIdx.x * 16 + tid] = 0u;
    f32x4 acc[2] = {};
    const unsigned short* Brow = phiT + (size_t)(n0 + l15) * PIX + kbase + q8;
    const float* X0 = x + (size_t)l15 * PIX + kbase + q8;
    const float* X1 = x + (size_t)(16 + l15) * PIX + kbase + q8;
    #pragma unroll 4
    for (int kk = 0; kk < PIX / 8; kk += 32) {
        bf16x8 bg = ldfrag_g(Brow + kk);
        float4 xa0 = *(const float4*)(X0 + kk), xb0 = *(const float4*)(X0 + kk + 4);
        float4 xa1 = *(const float4*)(X1 + kk), xb1 = *(const float4*)(X1 + kk + 4);
        bf16x8 a0, a1;
        a0[0]=(__bf16)xa0.x; a0[1]=(__bf16)xa0.y; a0[2]=(__bf16)xa0.z; a0[3]=(__bf16)xa0.w;
        a0[4]=(__bf16)xb0.x; a0[5]=(__bf16)xb0.y; a0[6]=(__bf16)xb0.z; a0[7]=(__bf16)xb0.w;
        a1[0]=(__bf16)xa1.x; a1[1]=(__bf16)xa1.y; a1[2]=(__bf16)xa1.z; a1[3]=(__bf16)xa1.w;
        a1[4]=(__bf16)xb1.x; a1[5]=(__bf16)xb1.y; a1[6]=(__bf16)xb1.z; a1[7]=(__bf16)xb1.w;
        acc[0] = __builtin_amdgcn_mfma_f32_16x16x32_bf16(a0, bg, acc[0], 0, 0, 0);
        acc[1] = __builtin_amdgcn_mfma_f32_16x16x32_bf16(a1, bg, acc[1], 0, 0, 0);
    }
    const int q = lane >> 4;
    #pragma unroll
    for (int mt = 0; mt < 2; ++mt)
        #pragma unroll
        for (int r = 0; r < 4; ++r)
            red[w * 512 + (mt * 16 + q * 4 + r) * 16 + l15] = acc[mt][r];
    __syncthreads();
    float s = 0.f;
    #pragma unroll
    for (int w8 = 0; w8 < 8; ++w8) s += red[w8 * 512 + tid];
    const int m = tid >> 4, n = n0 + (tid & 15);
    b[(size_t)m * NEU + n] = s;
}

// ---------------------------------------------------------------------------
// publish this thread's two a-values into rotating buffer (write-through 4-B
// agent stores; lane-pair packing => one store per pair)
__device__ __forceinline__ void publish(unsigned int* dst, size_t idx0, size_t idx1,
                                        float av0, float av1, int tid) {
    unsigned int p0 = f2b(av0), p1 = f2b(av1);
    unsigned int t0 = (unsigned int)__shfl_xor((int)p0, 1, 64);
    unsigned int t1 = (unsigned int)__shfl_xor((int)p1, 1, 64);
    if ((tid & 1) == 0) {
        __hip_atomic_store(dst + (idx0 >> 1), p0 | (t0 << 16),
                           __ATOMIC_RELAXED, __HIP_MEMORY_SCOPE_AGENT);
        __hip_atomic_store(dst + (idx1 >> 1), p1 | (t1 << 16),
                           __ATOMIC_RELAXED, __HIP_MEMORY_SCOPE_AGENT);
    }
}

// producer-side epoch bump: all 512 threads' write-through publish stores are
// individually vmcnt(0)-drained at the barrier, so data is at L3 before the
// flag store issues.
__device__ __forceinline__ void setflag(unsigned int* arr, unsigned int e,
                                        int tid, int bx) {
    __syncthreads();
    if (tid == 0)
        __hip_atomic_store(arr + bx * 16, e, __ATOMIC_RELAXED, __HIP_MEMORY_SCOPE_AGENT);
}

// ---------------------------------------------------------------------------
// Persistent kernel. 128 blocks x 512 thr; block owns 32 columns.
// a exchanged via 98 ROTATING buffers: every line written once (write-through)
// and read once (normal pipelined loads) => no stale-L2 risk.
//
// SYNC: no grid barrier.  Per-producer epoch flags (arr[p*16], 64-B padded).
// Fragment f of wave w covers k in [kbase+32f, kbase+32f+32) == producer
// block p = 16w+f's 32 owned columns, so wave w gates only on ITS 16
// producers (lanes ballot on flag[16w + (lane&15)] >= step) and releases
// independently -- no 128-wide convergence round-trip, no post-poll block
// barrier.  Skew is bounded at 1 step by the dense dependency itself; the
// red-buffer hazard stays fenced by the two per-step __syncthreads.
__global__ void __launch_bounds__(TPB, 2)
lca_persist(const unsigned short* G, const float* b,
            unsigned short* rot, float* aout, const float* lamp,
            unsigned int* arr) {
    __shared__ float red[8 * 1024];
    const int tid  = threadIdx.x;
    const int lane = tid & 63, w = tid >> 6;        // 8 waves
    const int l15  = lane & 15, q = lane >> 4;
    const int q8   = q * 8;
    const int n0   = blockIdx.x * 32;               // 32 columns per block
    const int kbase = w * (NEU / 8);                // 512 k per wave
    const int pbase = w * 16;                       // first producer of this wave

    // --- G fragments: 2 n-tiles x 16 k-frags.  Normal pipelined loads; no
    // __restrict__ anywhere => publish stores may alias => remat illegal.
    bf16x8 gf[2][16];
    #pragma unroll
    for (int j = 0; j < 2; ++j)
        #pragma unroll
        for (int f = 0; f < 16; ++f)
            gf[j][f] = ldfrag_g(G + (size_t)(n0 + j * 16 + l15) * NEU + kbase + f * 32 + q8);

    // --- per-thread state: outputs o0 = tid, o1 = tid + 512 (o = m*32 + nn) ---
    const int m0i = tid >> 5,         nn0 = tid & 31;
    const int m1i = (tid + 512) >> 5;
    const size_t idx0 = (size_t)m0i * NEU + n0 + nn0;
    const size_t idx1 = (size_t)m1i * NEU + n0 + nn0;
    const float bv0 = b[idx0], bv1 = b[idx1];
    const float lam = lamp[0];

    // --- step 0 entirely in-register: u1 = ETA*b, a1 = soft(u1) ---
    float uv0 = ETA * bv0, uv1 = ETA * bv1;
    float av0 = softt(uv0, lam), av1 = softt(uv1, lam);

    const size_t aoff0 = (size_t)l15 * NEU + kbase + q8;         // halves
    const size_t aoff1 = (size_t)(16 + l15) * NEU + kbase + q8;

    publish((unsigned int*)rot, idx0, idx1, av0, av1, tid);      // rot[0]
    setflag(arr, 1u, tid, blockIdx.x);

    for (int step = 1; step < STEPS; ++step) {       // steps 1..98
        const unsigned short* A = rot + (size_t)(step - 1) * SLOT;

        // wait for THIS wave's 16 producers to have published slot step-1
        {
            const unsigned int* fp = arr + (size_t)(pbase + l15) * 16;
            for (;;) {
                unsigned int v = __hip_atomic_load(fp, __ATOMIC_RELAXED,
                                                   __HIP_MEMORY_SCOPE_AGENT);
                if (__ballot(v < (unsigned int)step) == 0ULL) break;
                __builtin_amdgcn_s_sleep(1);
            }
            asm volatile("" ::: "memory");   // no load hoisting above the wait
        }

        f32x4 acc00 = {}, acc01 = {}, acc10 = {}, acc11 = {};
        #pragma unroll
        for (int h = 0; h < 2; ++h) {                // 2 batches of 8 frags
            bf16x8 s0[8], s1[8];
            #pragma unroll
            for (int f = 0; f < 8; ++f) {
                s0[f] = ldfrag_g(A + aoff0 + (h * 8 + f) * 32);
                s1[f] = ldfrag_g(A + aoff1 + (h * 8 + f) * 32);
            }
            #pragma unroll
            for (int f = 0; f < 8; ++f) {
                const int g = h * 8 + f;
                acc00 = __builtin_amdgcn_mfma_f32_16x16x32_bf16(s0[f], gf[0][g], acc00, 0, 0, 0);
                acc01 = __builtin_amdgcn_mfma_f32_16x16x32_bf16(s0[f], gf[1][g], acc01, 0, 0, 0);
                acc10 = __builtin_amdgcn_mfma_f32_16x16x32_bf16(s1[f], gf[0][g], acc10, 0, 0, 0);
                acc11 = __builtin_amdgcn_mfma_f32_16x16x32_bf16(s1[f], gf[1][g], acc11, 0, 0, 0);
            }
        }
        // stage partials: red[w][ m*32 + nn ],  m = mt*16 + q*4 + r, nn = j*16 + l15
        #pragma unroll
        for (int r = 0; r < 4; ++r) {
            red[w * 1024 + (q * 4 + r) * 32 + l15]           = acc00[r];
            red[w * 1024 + (q * 4 + r) * 32 + 16 + l15]      = acc01[r];
            red[w * 1024 + (16 + q * 4 + r) * 32 + l15]      = acc10[r];
            red[w * 1024 + (16 + q * 4 + r) * 32 + 16 + l15] = acc11[r];
        }
        __syncthreads();
        float s0 = 0.f, s1 = 0.f;
        #pragma unroll
        for (int w8 = 0; w8 < 8; ++w8) {
            s0 += red[w8 * 1024 + tid];
            s1 += red[w8 * 1024 + 512 + tid];
        }
        uv0 = fmaf(ETA, bv0 - s0 + av0 - uv0, uv0);
        uv1 = fmaf(ETA, bv1 - s1 + av1 - uv1, uv1);
        av0 = softt(uv0, lam);
        av1 = softt(uv1, lam);

        if (step == STEPS - 1) {
            aout[idx0] = av0;
            aout[idx1] = av1;
        } else {
            publish((unsigned int*)(rot + (size_t)step * SLOT), idx0, idx1, av0, av1, tid);
            setflag(arr, (unsigned int)(step + 1), tid, blockIdx.x);
        }
    }
}

// ===========================================================================
// Fallback fp32 path (round-1, known correct) for small ws_size
// ===========================================================================
__global__ void lca_init_f(const float* __restrict__ x, const float* __restrict__ phi,
                           float* __restrict__ b, float* __restrict__ u,
                           float* __restrict__ a) {
    const int n  = blockIdx.x * 64 + (threadIdx.x & 63);
    const int bi = blockIdx.y * 4 + (threadIdx.x >> 6);
    const float* xr = x + bi * PIX;
    float acc = 0.f;
    #pragma unroll 4
    for (int p = 0; p < PIX; ++p) acc = fmaf(xr[p], phi[p * NEU + n], acc);
    const int idx = bi * NEU + n;
    b[idx] = acc; u[idx] = 0.f; a[idx] = 0.f;
}
__global__ void lca_s_f(const float* __restrict__ a, const float* __restrict__ phi,
                        float* __restrict__ s) {
    const int lane = threadIdx.x & 63, w = threadIdx.x >> 6;
    const int bi = blockIdx.y, p0 = (blockIdx.x * 4 + w) * 8;
    const float* ar = a + bi * NEU;
    float acc[8] = {};
    for (int i = 0; i < NEU / 64; ++i) {
        const int n = i * 64 + lane;
        const float av = ar[n];
        #pragma unroll
        for (int j = 0; j < 8; ++j) acc[j] = fmaf(av, phi[(p0 + j) * NEU + n], acc[j]);
    }
    float out = 0.f;
    #pragma unroll
    for (int j = 0; j < 8; ++j) {
        float v = acc[j];
        v += __shfl_xor(v, 1, 64); v += __shfl_xor(v, 2, 64); v += __shfl_xor(v, 4, 64);
        v += __shfl_xor(v, 8, 64); v += __shfl_xor(v, 16, 64); v += __shfl_xor(v, 32, 64);
        if (lane == j) out = v;
    }
    if (lane < 8) s[bi * PIX + p0 + lane] = out;
}
__global__ void lca_t_f(const float* __restrict__ s, const float* __restrict__ phi,
                        const float* __restrict__ b, float* __restrict__ u,
                        float* __restrict__ a, const float* __restrict__ lamp) {
    __shared__ float ls[8 * 256];
    const int n = blockIdx.x * 64 + (threadIdx.x & 63);
    const int slot = threadIdx.x >> 6;
    const int bb = blockIdx.y * 8 + slot;
    float acc = 0.f;
    for (int c = 0; c < PIX; c += 256) {
        __syncthreads();
        for (int e = threadIdx.x; e < 8 * 256; e += 512) {
            const int r = e >> 8, p = e & 255;
            ls[e] = s[(blockIdx.y * 8 + r) * PIX + c + p];
        }
        __syncthreads();
        const float* lrow = ls + slot * 256;
        #pragma unroll 8
        for (int p = 0; p < 256; ++p) acc = fmaf(lrow[p], phi[(c + p) * NEU + n], acc);
    }
    const float lam = lamp[0];
    const int idx = bb * NEU + n;
    const float uo = u[idx];
    const float du = b[idx] - acc + a[idx] - uo;
    const float un = fmaf(ETA, du, uo);
    u[idx] = un; a[idx] = softt(un, lam);
}

// ===========================================================================
extern "C" void kernel_launch(void* const* d_in, const int* in_sizes, int n_in,
                              void* d_out, int out_size, void* d_ws, size_t ws_size,
                              hipStream_t stream) {
    const float* x    = (const float*)d_in[0];
    const float* phi  = (const float*)d_in[1];
    const float* lamp = (const float*)d_in[2];
    float* a = (float*)d_out;
    char* ws = (char*)d_ws;

    // rot region (98 x 256 KB) overlays phiT (24 MB): phiT is dead once
    // lca_binit completes, before lca_persist starts.
    const size_t ROT_OFF  = 0;
    const size_t ROT_BYTES= (size_t)(STEPS - 1) * SLOT * 2;         // 25.69 MB
    const size_t PHIT_OFF = 0;                                       // overlay
    const size_t G_OFF    = ROT_OFF + ROT_BYTES;                     // 25.69 MB
    const size_t B_OFF    = G_OFF + (size_t)NEU * NEU * 2;           // +32 MB
    const size_t ARR_OFF  = B_OFF + (size_t)BATCH * NEU * 4;
    const size_t NEED     = ARR_OFF + (size_t)NBLK * 64;             // ~57.0 MB

    if (ws_size >= NEED) {
        unsigned short* phiT = (unsigned short*)(ws + PHIT_OFF);
        unsigned short* rot  = (unsigned short*)(ws + ROT_OFF);
        unsigned short* G    = (unsigned short*)(ws + G_OFF);
        float*          b    = (float*)(ws + B_OFF);
        unsigned int*   arr  = (unsigned int*)(ws + ARR_OFF);

        transp<<<dim3(NEU / 64, PIX / 64), 256, 0, stream>>>(phi, phiT);
        gemm_G<<<dim3(32, 32), 256, 0, stream>>>(phiT, G);
        lca_binit<<<256, 512, 0, stream>>>(x, phiT, b, arr);

        void* args[6];
        const unsigned short* Gc = G;
        const float* bc = b;
        const float* lc = lamp;
        args[0] = (void*)&Gc;
        args[1] = (void*)&bc;
        args[2] = (void*)&rot;
        args[3] = (void*)&a;
        args[4] = (void*)&lc;
        args[5] = (void*)&arr;
        hipLaunchCooperativeKernel((const void*)lca_persist, dim3(NBLK), dim3(TPB),
                                   args, 0, stream);
    } else {
        float* fws = (float*)d_ws;
        float* b = fws;
        float* u = fws + BATCH * NEU;
        float* s = fws + 2 * BATCH * NEU;
        lca_init_f<<<dim3(64, 8), 256, 0, stream>>>(x, phi, b, u, a);
        for (int it = 0; it < STEPS; ++it) {
            lca_s_f<<<dim3(96, 32), 256, 0, stream>>>(a, phi, s);
            lca_t_f<<<dim3(64, 4), 512, 0, stream>>>(s, phi, b, u, a, lamp);
        }
    }
}

// Round 2
// 1113.447 us; speedup vs baseline: 1.0413x; 1.0044x over previous
//
#include <hip/hip_runtime.h>

#define BATCH 32
#define PIX   3072
#define NEU   4096
#define STEPS 99           // reference runs NUM_STEPS-1 = 99 update iterations
#define ETA   (0.001f / 0.03f)
#define NBLK  128
#define TPB   512
#define SLOT  (BATCH * NEU)          // halves per rotating a-buffer (256 KB)

typedef __bf16 bf16x8 __attribute__((ext_vector_type(8)));
typedef float  f32x4  __attribute__((ext_vector_type(4)));

__device__ __forceinline__ float softt(float u, float lam) {
    return u > lam ? u - lam : (u < -lam ? u + lam : 0.0f);
}

// fp32 -> bf16 round-to-nearest-even
__device__ __forceinline__ unsigned short f2b(float f) {
    unsigned int u = __builtin_bit_cast(unsigned int, f);
    u = (u + 0x7FFFu + ((u >> 16) & 1u)) >> 16;
    return (unsigned short)u;
}

__device__ __forceinline__ bf16x8 ldfrag_g(const unsigned short* p) {
    uint4 v = *(const uint4*)p;
    return __builtin_bit_cast(bf16x8, v);
}

// ---------------------------------------------------------------------------
// φ (fp32 [PIX][NEU]) -> φT (bf16 [NEU][PIX]).  64x64 tiles via LDS.
__global__ void transp(const float* __restrict__ phi, unsigned short* __restrict__ phiT) {
    __shared__ float t[64][65];
    const int n0 = blockIdx.x * 64, p0 = blockIdx.y * 64;
    const int tid = threadIdx.x;
    #pragma unroll
    for (int pass = 0; pass < 4; ++pass) {
        const int r  = pass * 16 + (tid >> 4);
        const int c4 = (tid & 15) * 4;
        float4 v = *(const float4*)(phi + (size_t)(p0 + r) * NEU + n0 + c4);
        t[r][c4 + 0] = v.x; t[r][c4 + 1] = v.y; t[r][c4 + 2] = v.z; t[r][c4 + 3] = v.w;
    }
    __syncthreads();
    #pragma unroll
    for (int pass = 0; pass < 2; ++pass) {
        const int cp = pass * 32 + (tid >> 3);
        const int p8 = (tid & 7) * 8;
        unsigned int w0 = (unsigned int)f2b(t[p8 + 0][cp]) | ((unsigned int)f2b(t[p8 + 1][cp]) << 16);
        unsigned int w1 = (unsigned int)f2b(t[p8 + 2][cp]) | ((unsigned int)f2b(t[p8 + 3][cp]) << 16);
        unsigned int w2 = (unsigned int)f2b(t[p8 + 4][cp]) | ((unsigned int)f2b(t[p8 + 5][cp]) << 16);
        unsigned int w3 = (unsigned int)f2b(t[p8 + 6][cp]) | ((unsigned int)f2b(t[p8 + 7][cp]) << 16);
        uint4 o = make_uint4(w0, w1, w2, w3);
        *(uint4*)(phiT + (size_t)(n0 + cp) * PIX + p0 + p8) = o;
    }
}

// ---------------------------------------------------------------------------
// G = φᵀφ (symmetric, bf16). Upper-triangle blocks only; mirror-store.
__global__ void gemm_G(const unsigned short* __restrict__ phiT, unsigned short* __restrict__ G) {
    if (blockIdx.y > blockIdx.x) return;
    __shared__ __align__(16) unsigned short lds[2][128 * 40];
    const int m0 = blockIdx.y * 128, n0 = blockIdx.x * 128;
    const int tid  = threadIdx.x;
    const int lane = tid & 63, w = tid >> 6;
    const int wm = (w & 1) * 64, wn = (w >> 1) * 64;
    const int q8 = (lane >> 4) * 8, l15 = lane & 15;
    f32x4 acc[4][4] = {};
    for (int k0 = 0; k0 < PIX; k0 += 32) {
        __syncthreads();
        #pragma unroll
        for (int it = 0; it < 2; ++it) {
            const int id = tid + 256 * it;
            const int row = id >> 2, q = id & 3;
            uint4 va = *(const uint4*)(phiT + (size_t)(m0 + row) * PIX + k0 + q * 8);
            *(uint4*)(&lds[0][row * 40 + q * 8]) = va;
            uint4 vb = *(const uint4*)(phiT + (size_t)(n0 + row) * PIX + k0 + q * 8);
            *(uint4*)(&lds[1][row * 40 + q * 8]) = vb;
        }
        __syncthreads();
        bf16x8 af[4], bfr[4];
        #pragma unroll
        for (int i = 0; i < 4; ++i) {
            af[i]  = *(const bf16x8*)(&lds[0][(wm + i * 16 + l15) * 40 + q8]);
            bfr[i] = *(const bf16x8*)(&lds[1][(wn + i * 16 + l15) * 40 + q8]);
        }
        #pragma unroll
        for (int i = 0; i < 4; ++i)
            #pragma unroll
            for (int j = 0; j < 4; ++j)
                acc[i][j] = __builtin_amdgcn_mfma_f32_16x16x32_bf16(af[i], bfr[j], acc[i][j], 0, 0, 0);
    }
    const int q = lane >> 4;
    const bool offdiag = (blockIdx.y != blockIdx.x);
    #pragma unroll
    for (int i = 0; i < 4; ++i)
        #pragma unroll
        for (int j = 0; j < 4; ++j) {
            unsigned short pk[4];
            #pragma unroll
            for (int r = 0; r < 4; ++r) {
                const int gm = m0 + wm + i * 16 + q * 4 + r;
                const int gn = n0 + wn + j * 16 + l15;
                const unsigned short v = f2b(acc[i][j][r]);
                G[(size_t)gm * NEU + gn] = v;
                pk[r] = v;
            }
            if (offdiag) {
                const int gm0 = m0 + wm + i * 16 + q * 4;
                const int gn  = n0 + wn + j * 16 + l15;
                *(ushort4*)(G + (size_t)gn * NEU + gm0) = make_ushort4(pk[0], pk[1], pk[2], pk[3]);
            }
        }
}

// ---------------------------------------------------------------------------
// b = x @ phi; zero the 128 producer flags (64-B padded).
// grid 256 (16-col strips), block 512
__global__ void lca_binit(const float* __restrict__ x, const unsigned short* __restrict__ phiT,
                          float* __restrict__ b, unsigned int* __restrict__ arr) {
    __shared__ float red[8 * 512];
    const int tid = threadIdx.x;
    const int lane = tid & 63, w = tid >> 6;
    const int n0 = blockIdx.x * 16;
    const int kbase = w * (PIX / 8);
    const int q8 = (lane >> 4) * 8, l15 = lane & 15;
    if (blockIdx.x < NBLK && tid < 16) arr[blockIdx.x * 16 + tid] = 0u;
    f32x4 acc[2] = {};
    const unsigned short* Brow = phiT + (size_t)(n0 + l15) * PIX + kbase + q8;
    const float* X0 = x + (size_t)l15 * PIX + kbase + q8;
    const float* X1 = x + (size_t)(16 + l15) * PIX + kbase + q8;
    #pragma unroll 4
    for (int kk = 0; kk < PIX / 8; kk += 32) {
        bf16x8 bg = ldfrag_g(Brow + kk);
        float4 xa0 = *(const float4*)(X0 + kk), xb0 = *(const float4*)(X0 + kk + 4);
        float4 xa1 = *(const float4*)(X1 + kk), xb1 = *(const float4*)(X1 + kk + 4);
        bf16x8 a0, a1;
        a0[0]=(__bf16)xa0.x; a0[1]=(__bf16)xa0.y; a0[2]=(__bf16)xa0.z; a0[3]=(__bf16)xa0.w;
        a0[4]=(__bf16)xb0.x; a0[5]=(__bf16)xb0.y; a0[6]=(__bf16)xb0.z; a0[7]=(__bf16)xb0.w;
        a1[0]=(__bf16)xa1.x; a1[1]=(__bf16)xa1.y; a1[2]=(__bf16)xa1.z; a1[3]=(__bf16)xa1.w;
        a1[4]=(__bf16)xb1.x; a1[5]=(__bf16)xb1.y; a1[6]=(__bf16)xb1.z; a1[7]=(__bf16)xb1.w;
        acc[0] = __builtin_amdgcn_mfma_f32_16x16x32_bf16(a0, bg, acc[0], 0, 0, 0);
        acc[1] = __builtin_amdgcn_mfma_f32_16x16x32_bf16(a1, bg, acc[1], 0, 0, 0);
    }
    const int q = lane >> 4;
    #pragma unroll
    for (int mt = 0; mt < 2; ++mt)
        #pragma unroll
        for (int r = 0; r < 4; ++r)
            red[w * 512 + (mt * 16 + q * 4 + r) * 16 + l15] = acc[mt][r];
    __syncthreads();
    float s = 0.f;
    #pragma unroll
    for (int w8 = 0; w8 < 8; ++w8) s += red[w8 * 512 + tid];
    const int m = tid >> 4, n = n0 + (tid & 15);
    b[(size_t)m * NEU + n] = s;
}

// ---------------------------------------------------------------------------
// publish this thread's two a-values into rotating buffer (write-through 4-B
// agent stores; lane-pair packing => one store per pair)
__device__ __forceinline__ void publish(unsigned int* dst, size_t idx0, size_t idx1,
                                        float av0, float av1, int tid) {
    unsigned int p0 = f2b(av0), p1 = f2b(av1);
    unsigned int t0 = (unsigned int)__shfl_xor((int)p0, 1, 64);
    unsigned int t1 = (unsigned int)__shfl_xor((int)p1, 1, 64);
    if ((tid & 1) == 0) {
        __hip_atomic_store(dst + (idx0 >> 1), p0 | (t0 << 16),
                           __ATOMIC_RELAXED, __HIP_MEMORY_SCOPE_AGENT);
        __hip_atomic_store(dst + (idx1 >> 1), p1 | (t1 << 16),
                           __ATOMIC_RELAXED, __HIP_MEMORY_SCOPE_AGENT);
    }
}

// producer-side epoch bump: all 512 threads' write-through publish stores are
// individually vmcnt(0)-drained at the barrier, so data is at L3 before the
// flag store issues.
__device__ __forceinline__ void setflag(unsigned int* arr, unsigned int e,
                                        int tid, int bx) {
    __syncthreads();
    if (tid == 0)
        __hip_atomic_store(arr + bx * 16, e, __ATOMIC_RELAXED, __HIP_MEMORY_SCOPE_AGENT);
}

// ---------------------------------------------------------------------------
// Persistent kernel. 128 blocks x 512 thr; block owns 32 columns.
// a exchanged via 98 ROTATING buffers: every line written once (write-through)
// and read once (normal pipelined loads) => no stale-L2 risk.
//
// SYNC: per-producer epoch flags; wave w gates only on ITS 16 producers.
//
// CODEGEN: all params __restrict__ (workspace regions are disjoint), G
// fragments pinned live in VGPRs via empty asm (blocks remat-from-G), and
// the anti-hoist fence after the poll is a false dependency on the A pointer
// ONLY -- no full "memory" clobber anywhere in the loop, so the compiler can
// keep gf resident and pipeline the body.
__global__ void __launch_bounds__(TPB, 2)
lca_persist(const unsigned short* __restrict__ G, const float* __restrict__ b,
            unsigned short* __restrict__ rot, float* __restrict__ aout,
            const float* __restrict__ lamp, unsigned int* __restrict__ arr) {
    __shared__ float red[8 * 1024];
    const int tid  = threadIdx.x;
    const int lane = tid & 63, w = tid >> 6;        // 8 waves
    const int l15  = lane & 15, q = lane >> 4;
    const int q8   = q * 8;
    const int n0   = blockIdx.x * 32;               // 32 columns per block
    const int kbase = w * (NEU / 8);                // 512 k per wave
    const int pbase = w * 16;                       // first producer of this wave

    // --- G fragments: 2 n-tiles x 16 k-frags, loaded ONCE, pinned resident.
    bf16x8 gf[2][16];
    #pragma unroll
    for (int j = 0; j < 2; ++j)
        #pragma unroll
        for (int f = 0; f < 16; ++f)
            gf[j][f] = ldfrag_g(G + (size_t)(n0 + j * 16 + l15) * NEU + kbase + f * 32 + q8);
    // pin: make each fragment an opaque asm result so the compiler can neither
    // rematerialize it from G inside the loop nor sink the loads.
    #pragma unroll
    for (int j = 0; j < 2; ++j)
        #pragma unroll
        for (int f = 0; f < 16; ++f)
            asm volatile("" : "+v"(gf[j][f]));

    // --- per-thread state: outputs o0 = tid, o1 = tid + 512 (o = m*32 + nn) ---
    const int m0i = tid >> 5,         nn0 = tid & 31;
    const int m1i = (tid + 512) >> 5;
    const size_t idx0 = (size_t)m0i * NEU + n0 + nn0;
    const size_t idx1 = (size_t)m1i * NEU + n0 + nn0;
    const float bv0 = b[idx0], bv1 = b[idx1];
    const float lam = lamp[0];

    // --- step 0 entirely in-register: u1 = ETA*b, a1 = soft(u1) ---
    float uv0 = ETA * bv0, uv1 = ETA * bv1;
    float av0 = softt(uv0, lam), av1 = softt(uv1, lam);

    const size_t aoff0 = (size_t)l15 * NEU + kbase + q8;         // halves
    const size_t aoff1 = (size_t)(16 + l15) * NEU + kbase + q8;

    publish((unsigned int*)rot, idx0, idx1, av0, av1, tid);      // rot[0]
    setflag(arr, 1u, tid, blockIdx.x);

    for (int step = 1; step < STEPS; ++step) {       // steps 1..98
        const unsigned short* A = rot + (size_t)(step - 1) * SLOT;

        // wait for THIS wave's 16 producers to have published slot step-1
        {
            const unsigned int* fp = arr + (size_t)(pbase + l15) * 16;
            for (;;) {
                unsigned int v = __hip_atomic_load(fp, __ATOMIC_RELAXED,
                                                   __HIP_MEMORY_SCOPE_AGENT);
                if (__ballot(v < (unsigned int)step) == 0ULL) break;
            }
            // order the A-loads after the poll WITHOUT clobbering all memory:
            // false dependency on the pointer the loads use.
            asm volatile("" : "+s"(A));
        }

        f32x4 acc00 = {}, acc01 = {}, acc10 = {}, acc11 = {};
        #pragma unroll
        for (int h = 0; h < 2; ++h) {                // 2 batches of 8 frags
            bf16x8 s0[8], s1[8];
            #pragma unroll
            for (int f = 0; f < 8; ++f) {
                s0[f] = ldfrag_g(A + aoff0 + (h * 8 + f) * 32);
                s1[f] = ldfrag_g(A + aoff1 + (h * 8 + f) * 32);
            }
            #pragma unroll
            for (int f = 0; f < 8; ++f) {
                const int g = h * 8 + f;
                acc00 = __builtin_amdgcn_mfma_f32_16x16x32_bf16(s0[f], gf[0][g], acc00, 0, 0, 0);
                acc01 = __builtin_amdgcn_mfma_f32_16x16x32_bf16(s0[f], gf[1][g], acc01, 0, 0, 0);
                acc10 = __builtin_amdgcn_mfma_f32_16x16x32_bf16(s1[f], gf[0][g], acc10, 0, 0, 0);
                acc11 = __builtin_amdgcn_mfma_f32_16x16x32_bf16(s1[f], gf[1][g], acc11, 0, 0, 0);
            }
        }
        // stage partials: red[w][ m*32 + nn ],  m = mt*16 + q*4 + r, nn = j*16 + l15
        #pragma unroll
        for (int r = 0; r < 4; ++r) {
            red[w * 1024 + (q * 4 + r) * 32 + l15]           = acc00[r];
            red[w * 1024 + (q * 4 + r) * 32 + 16 + l15]      = acc01[r];
            red[w * 1024 + (16 + q * 4 + r) * 32 + l15]      = acc10[r];
            red[w * 1024 + (16 + q * 4 + r) * 32 + 16 + l15] = acc11[r];
        }
        __syncthreads();
        float s0 = 0.f, s1 = 0.f;
        #pragma unroll
        for (int w8 = 0; w8 < 8; ++w8) {
            s0 += red[w8 * 1024 + tid];
            s1 += red[w8 * 1024 + 512 + tid];
        }
        uv0 = fmaf(ETA, bv0 - s0 + av0 - uv0, uv0);
        uv1 = fmaf(ETA, bv1 - s1 + av1 - uv1, uv1);
        av0 = softt(uv0, lam);
        av1 = softt(uv1, lam);

        if (step == STEPS - 1) {
            aout[idx0] = av0;
            aout[idx1] = av1;
        } else {
            publish((unsigned int*)(rot + (size_t)step * SLOT), idx0, idx1, av0, av1, tid);
            setflag(arr, (unsigned int)(step + 1), tid, blockIdx.x);
        }
    }
}

// ===========================================================================
// Fallback fp32 path (round-1, known correct) for small ws_size
// ===========================================================================
__global__ void lca_init_f(const float* __restrict__ x, const float* __restrict__ phi,
                           float* __restrict__ b, float* __restrict__ u,
                           float* __restrict__ a) {
    const int n  = blockIdx.x * 64 + (threadIdx.x & 63);
    const int bi = blockIdx.y * 4 + (threadIdx.x >> 6);
    const float* xr = x + bi * PIX;
    float acc = 0.f;
    #pragma unroll 4
    for (int p = 0; p < PIX; ++p) acc = fmaf(xr[p], phi[p * NEU + n], acc);
    const int idx = bi * NEU + n;
    b[idx] = acc; u[idx] = 0.f; a[idx] = 0.f;
}
__global__ void lca_s_f(const float* __restrict__ a, const float* __restrict__ phi,
                        float* __restrict__ s) {
    const int lane = threadIdx.x & 63, w = threadIdx.x >> 6;
    const int bi = blockIdx.y, p0 = (blockIdx.x * 4 + w) * 8;
    const float* ar = a + bi * NEU;
    float acc[8] = {};
    for (int i = 0; i < NEU / 64; ++i) {
        const int n = i * 64 + lane;
        const float av = ar[n];
        #pragma unroll
        for (int j = 0; j < 8; ++j) acc[j] = fmaf(av, phi[(p0 + j) * NEU + n], acc[j]);
    }
    float out = 0.f;
    #pragma unroll
    for (int j = 0; j < 8; ++j) {
        float v = acc[j];
        v += __shfl_xor(v, 1, 64); v += __shfl_xor(v, 2, 64); v += __shfl_xor(v, 4, 64);
        v += __shfl_xor(v, 8, 64); v += __shfl_xor(v, 16, 64); v += __shfl_xor(v, 32, 64);
        if (lane == j) out = v;
    }
    if (lane < 8) s[bi * PIX + p0 + lane] = out;
}
__global__ void lca_t_f(const float* __restrict__ s, const float* __restrict__ phi,
                        const float* __restrict__ b, float* __restrict__ u,
                        float* __restrict__ a, const float* __restrict__ lamp) {
    __shared__ float ls[8 * 256];
    const int n = blockIdx.x * 64 + (threadIdx.x & 63);
    const int slot = threadIdx.x >> 6;
    const int bb = blockIdx.y * 8 + slot;
    float acc = 0.f;
    for (int c = 0; c < PIX; c += 256) {
        __syncthreads();
        for (int e = threadIdx.x; e < 8 * 256; e += 512) {
            const int r = e >> 8, p = e & 255;
            ls[e] = s[(blockIdx.y * 8 + r) * PIX + c + p];
        }
        __syncthreads();
        const float* lrow = ls + slot * 256;
        #pragma unroll 8
        for (int p = 0; p < 256; ++p) acc = fmaf(lrow[p], phi[(c + p) * NEU + n], acc);
    }
    const float lam = lamp[0];
    const int idx = bb * NEU + n;
    const float uo = u[idx];
    const float du = b[idx] - acc + a[idx] - uo;
    const float un = fmaf(ETA, du, uo);
    u[idx] = un; a[idx] = softt(un, lam);
}

// ===========================================================================
extern "C" void kernel_launch(void* const* d_in, const int* in_sizes, int n_in,
                              void* d_out, int out_size, void* d_ws, size_t ws_size,
                              hipStream_t stream) {
    const float* x    = (const float*)d_in[0];
    const float* phi  = (const float*)d_in[1];
    const float* lamp = (const float*)d_in[2];
    float* a = (float*)d_out;
    char* ws = (char*)d_ws;

    // rot region (98 x 256 KB) overlays phiT (24 MB): phiT is dead once
    // lca_binit completes, before lca_persist starts.
    const size_t ROT_OFF  = 0;
    const size_t ROT_BYTES= (size_t)(STEPS - 1) * SLOT * 2;         // 25.69 MB
    const size_t PHIT_OFF = 0;                                       // overlay
    const size_t G_OFF    = ROT_OFF + ROT_BYTES;                     // 25.69 MB
    const size_t B_OFF    = G_OFF + (size_t)NEU * NEU * 2;           // +32 MB
    const size_t ARR_OFF  = B_OFF + (size_t)BATCH * NEU * 4;
    const size_t NEED     = ARR_OFF + (size_t)NBLK * 64;             // ~57.0 MB

    if (ws_size >= NEED) {
        unsigned short* phiT = (unsigned short*)(ws + PHIT_OFF);
        unsigned short* rot  = (unsigned short*)(ws + ROT_OFF);
        unsigned short* G    = (unsigned short*)(ws + G_OFF);
        float*          b    = (float*)(ws + B_OFF);
        unsigned int*   arr  = (unsigned int*)(ws + ARR_OFF);

        transp<<<dim3(NEU / 64, PIX / 64), 256, 0, stream>>>(phi, phiT);
        gemm_G<<<dim3(32, 32), 256, 0, stream>>>(phiT, G);
        lca_binit<<<256, 512, 0, stream>>>(x, phiT, b, arr);

        void* args[6];
        const unsigned short* Gc = G;
        const float* bc = b;
        const float* lc = lamp;
        args[0] = (void*)&Gc;
        args[1] = (void*)&bc;
        args[2] = (void*)&rot;
        args[3] = (void*)&a;
        args[4] = (void*)&lc;
        args[5] = (void*)&arr;
        hipLaunchCooperativeKernel((const void*)lca_persist, dim3(NBLK), dim3(TPB),
                                   args, 0, stream);
    } else {
        float* fws = (float*)d_ws;
        float* b = fws;
        float* u = fws + BATCH * NEU;
        float* s = fws + 2 * BATCH * NEU;
        lca_init_f<<<dim3(64, 8), 256, 0, stream>>>(x, phi, b, u, a);
        for (int it = 0; it < STEPS; ++it) {
            lca_s_f<<<dim3(96, 32), 256, 0, stream>>>(a, phi, s);
            lca_t_f<<<dim3(64, 4), 512, 0, stream>>>(s, phi, b, u, a, lamp);
        }
    }
}

// Round 3
// 819.415 us; speedup vs baseline: 1.4149x; 1.3588x over previous
//
#include <hip/hip_runtime.h>

#define BATCH 32
#define PIX   3072
#define NEU   4096
#define STEPS 99           // reference runs NUM_STEPS-1 = 99 update iterations
#define ETA   (0.001f / 0.03f)
#define NBLK  256          // 2 independent half-batch systems x 128 col-groups
#define TPB   512
#define SLOT  (BATCH * NEU)          // halves per rotating a-buffer (256 KB)

typedef __bf16 bf16x8 __attribute__((ext_vector_type(8)));
typedef float  f32x4  __attribute__((ext_vector_type(4)));

__device__ __forceinline__ float softt(float u, float lam) {
    return u > lam ? u - lam : (u < -lam ? u + lam : 0.0f);
}

// fp32 -> bf16 round-to-nearest-even
__device__ __forceinline__ unsigned short f2b(float f) {
    unsigned int u = __builtin_bit_cast(unsigned int, f);
    u = (u + 0x7FFFu + ((u >> 16) & 1u)) >> 16;
    return (unsigned short)u;
}

__device__ __forceinline__ bf16x8 ldfrag_g(const unsigned short* p) {
    uint4 v = *(const uint4*)p;
    return __builtin_bit_cast(bf16x8, v);
}

// ---------------------------------------------------------------------------
// φ (fp32 [PIX][NEU]) -> φT (bf16 [NEU][PIX]).  64x64 tiles via LDS.
__global__ void transp(const float* __restrict__ phi, unsigned short* __restrict__ phiT) {
    __shared__ float t[64][65];
    const int n0 = blockIdx.x * 64, p0 = blockIdx.y * 64;
    const int tid = threadIdx.x;
    #pragma unroll
    for (int pass = 0; pass < 4; ++pass) {
        const int r  = pass * 16 + (tid >> 4);
        const int c4 = (tid & 15) * 4;
        float4 v = *(const float4*)(phi + (size_t)(p0 + r) * NEU + n0 + c4);
        t[r][c4 + 0] = v.x; t[r][c4 + 1] = v.y; t[r][c4 + 2] = v.z; t[r][c4 + 3] = v.w;
    }
    __syncthreads();
    #pragma unroll
    for (int pass = 0; pass < 2; ++pass) {
        const int cp = pass * 32 + (tid >> 3);
        const int p8 = (tid & 7) * 8;
        unsigned int w0 = (unsigned int)f2b(t[p8 + 0][cp]) | ((unsigned int)f2b(t[p8 + 1][cp]) << 16);
        unsigned int w1 = (unsigned int)f2b(t[p8 + 2][cp]) | ((unsigned int)f2b(t[p8 + 3][cp]) << 16);
        unsigned int w2 = (unsigned int)f2b(t[p8 + 4][cp]) | ((unsigned int)f2b(t[p8 + 5][cp]) << 16);
        unsigned int w3 = (unsigned int)f2b(t[p8 + 6][cp]) | ((unsigned int)f2b(t[p8 + 7][cp]) << 16);
        uint4 o = make_uint4(w0, w1, w2, w3);
        *(uint4*)(phiT + (size_t)(n0 + cp) * PIX + p0 + p8) = o;
    }
}

// ---------------------------------------------------------------------------
// G = φᵀφ (symmetric, bf16). Upper-triangle blocks only; mirror-store.
__global__ void gemm_G(const unsigned short* __restrict__ phiT, unsigned short* __restrict__ G) {
    if (blockIdx.y > blockIdx.x) return;
    __shared__ __align__(16) unsigned short lds[2][128 * 40];
    const int m0 = blockIdx.y * 128, n0 = blockIdx.x * 128;
    const int tid  = threadIdx.x;
    const int lane = tid & 63, w = tid >> 6;
    const int wm = (w & 1) * 64, wn = (w >> 1) * 64;
    const int q8 = (lane >> 4) * 8, l15 = lane & 15;
    f32x4 acc[4][4] = {};
    for (int k0 = 0; k0 < PIX; k0 += 32) {
        __syncthreads();
        #pragma unroll
        for (int it = 0; it < 2; ++it) {
            const int id = tid + 256 * it;
            const int row = id >> 2, q = id & 3;
            uint4 va = *(const uint4*)(phiT + (size_t)(m0 + row) * PIX + k0 + q * 8);
            *(uint4*)(&lds[0][row * 40 + q * 8]) = va;
            uint4 vb = *(const uint4*)(phiT + (size_t)(n0 + row) * PIX + k0 + q * 8);
            *(uint4*)(&lds[1][row * 40 + q * 8]) = vb;
        }
        __syncthreads();
        bf16x8 af[4], bfr[4];
        #pragma unroll
        for (int i = 0; i < 4; ++i) {
            af[i]  = *(const bf16x8*)(&lds[0][(wm + i * 16 + l15) * 40 + q8]);
            bfr[i] = *(const bf16x8*)(&lds[1][(wn + i * 16 + l15) * 40 + q8]);
        }
        #pragma unroll
        for (int i = 0; i < 4; ++i)
            #pragma unroll
            for (int j = 0; j < 4; ++j)
                acc[i][j] = __builtin_amdgcn_mfma_f32_16x16x32_bf16(af[i], bfr[j], acc[i][j], 0, 0, 0);
    }
    const int q = lane >> 4;
    const bool offdiag = (blockIdx.y != blockIdx.x);
    #pragma unroll
    for (int i = 0; i < 4; ++i)
        #pragma unroll
        for (int j = 0; j < 4; ++j) {
            unsigned short pk[4];
            #pragma unroll
            for (int r = 0; r < 4; ++r) {
                const int gm = m0 + wm + i * 16 + q * 4 + r;
                const int gn = n0 + wn + j * 16 + l15;
                const unsigned short v = f2b(acc[i][j][r]);
                G[(size_t)gm * NEU + gn] = v;
                pk[r] = v;
            }
            if (offdiag) {
                const int gm0 = m0 + wm + i * 16 + q * 4;
                const int gn  = n0 + wn + j * 16 + l15;
                *(ushort4*)(G + (size_t)gn * NEU + gm0) = make_ushort4(pk[0], pk[1], pk[2], pk[3]);
            }
        }
}

// ---------------------------------------------------------------------------
// b = x @ phi; zero the 256 producer flags (64-B padded).
// grid 256 (16-col strips), block 512
__global__ void lca_binit(const float* __restrict__ x, const unsigned short* __restrict__ phiT,
                          float* __restrict__ b, unsigned int* __restrict__ arr) {
    __shared__ float red[8 * 512];
    const int tid = threadIdx.x;
    const int lane = tid & 63, w = tid >> 6;
    const int n0 = blockIdx.x * 16;
    const int kbase = w * (PIX / 8);
    const int q8 = (lane >> 4) * 8, l15 = lane & 15;
    if (blockIdx.x < NBLK && tid < 16) arr[blockIdx.x * 16 + tid] = 0u;
    f32x4 acc[2] = {};
    const unsigned short* Brow = phiT + (size_t)(n0 + l15) * PIX + kbase + q8;
    const float* X0 = x + (size_t)l15 * PIX + kbase + q8;
    const float* X1 = x + (size_t)(16 + l15) * PIX + kbase + q8;
    #pragma unroll 4
    for (int kk = 0; kk < PIX / 8; kk += 32) {
        bf16x8 bg = ldfrag_g(Brow + kk);
        float4 xa0 = *(const float4*)(X0 + kk), xb0 = *(const float4*)(X0 + kk + 4);
        float4 xa1 = *(const float4*)(X1 + kk), xb1 = *(const float4*)(X1 + kk + 4);
        bf16x8 a0, a1;
        a0[0]=(__bf16)xa0.x; a0[1]=(__bf16)xa0.y; a0[2]=(__bf16)xa0.z; a0[3]=(__bf16)xa0.w;
        a0[4]=(__bf16)xb0.x; a0[5]=(__bf16)xb0.y; a0[6]=(__bf16)xb0.z; a0[7]=(__bf16)xb0.w;
        a1[0]=(__bf16)xa1.x; a1[1]=(__bf16)xa1.y; a1[2]=(__bf16)xa1.z; a1[3]=(__bf16)xa1.w;
        a1[4]=(__bf16)xb1.x; a1[5]=(__bf16)xb1.y; a1[6]=(__bf16)xb1.z; a1[7]=(__bf16)xb1.w;
        acc[0] = __builtin_amdgcn_mfma_f32_16x16x32_bf16(a0, bg, acc[0], 0, 0, 0);
        acc[1] = __builtin_amdgcn_mfma_f32_16x16x32_bf16(a1, bg, acc[1], 0, 0, 0);
    }
    const int q = lane >> 4;
    #pragma unroll
    for (int mt = 0; mt < 2; ++mt)
        #pragma unroll
        for (int r = 0; r < 4; ++r)
            red[w * 512 + (mt * 16 + q * 4 + r) * 16 + l15] = acc[mt][r];
    __syncthreads();
    float s = 0.f;
    #pragma unroll
    for (int w8 = 0; w8 < 8; ++w8) s += red[w8 * 512 + tid];
    const int m = tid >> 4, n = n0 + (tid & 15);
    b[(size_t)m * NEU + n] = s;
}

// ---------------------------------------------------------------------------
// publish this thread's single a-value: gather 4 consecutive lanes' bf16
// pairs into one 8-B agent-scope write-through store (4x fewer L3 write
// transactions than per-pair dwords).
__device__ __forceinline__ void publish16(unsigned short* slot, size_t idx,
                                          float av, int lane) {
    unsigned int v  = f2b(av);
    unsigned int d0 = v | ((unsigned int)__shfl_xor((int)v, 1, 64) << 16);
    unsigned int hi = (unsigned int)__shfl_xor((int)d0, 2, 64);
    if ((lane & 3) == 0) {
        unsigned long long val = (unsigned long long)d0 | ((unsigned long long)hi << 32);
        __hip_atomic_store((unsigned long long*)slot + (idx >> 2), val,
                           __ATOMIC_RELAXED, __HIP_MEMORY_SCOPE_AGENT);
    }
}

// producer-side epoch bump: all 512 threads' write-through publish stores are
// individually vmcnt(0)-drained at the barrier, so data is at L3 before the
// flag store issues.
__device__ __forceinline__ void setflag(unsigned int* arr, unsigned int e,
                                        int tid, int bx) {
    __syncthreads();
    if (tid == 0)
        __hip_atomic_store(arr + bx * 16, e, __ATOMIC_RELAXED, __HIP_MEMORY_SCOPE_AGENT);
}

// ---------------------------------------------------------------------------
// Persistent kernel, 256 blocks x 512 thr -- ALL 256 CUs active.
//
// The 32 batch rows are 32 INDEPENDENT LCA systems (no cross-row coupling in
// a@G, u-update, or soft-threshold).  Split into two disjoint half-systems of
// 16 rows each: block bx = h*128 + c owns batch rows [16h,16h+16) x columns
// [32c,32c+32).  Per block everything halves vs the 128-block version: A-read
// 128 KB/step, 32 MFMAs/wave, 8x512-float reduce, 1 output/thread -- while
// the per-thread G footprint (n,k only) is unchanged.  No extra sync hop.
//
// SYNC: per-producer epoch flags; wave w gates only on its 16 producers of
// its own half (flags h*128 + 16w + l15).  Numerics are bit-identical to the
// previous version (same k-order, same 8-way reduce order).
__global__ void __launch_bounds__(TPB, 2)
lca_persist(const unsigned short* __restrict__ G, const float* __restrict__ b,
            unsigned short* __restrict__ rot, float* __restrict__ aout,
            const float* __restrict__ lamp, unsigned int* __restrict__ arr) {
    __shared__ float red[8 * 512];
    const int tid  = threadIdx.x;
    const int lane = tid & 63, w = tid >> 6;        // 8 waves
    const int l15  = lane & 15, q = lane >> 4;
    const int q8   = q * 8;
    const int c    = blockIdx.x & 127;              // column group (32 cols)
    const int h    = blockIdx.x >> 7;               // batch half (16 rows)
    const int n0   = c * 32;
    const int rb   = h * 16;                        // first batch row
    const int kbase = w * (NEU / 8);                // 512 k per wave
    const int pbase = h * 128 + w * 16;             // first producer flag

    // --- G fragments: 2 n-tiles x 16 k-frags, loaded once, loop-invariant.
    bf16x8 gf[2][16];
    #pragma unroll
    for (int j = 0; j < 2; ++j)
        #pragma unroll
        for (int f = 0; f < 16; ++f)
            gf[j][f] = ldfrag_g(G + (size_t)(n0 + j * 16 + l15) * NEU + kbase + f * 32 + q8);

    // --- per-thread state: ONE output (row = rb + tid>>5, col = n0 + tid&31)
    const int m0i = tid >> 5, nn0 = tid & 31;
    const size_t idx0 = (size_t)(rb + m0i) * NEU + n0 + nn0;
    const float bv0 = b[idx0];
    const float lam = lamp[0];

    // --- step 0 entirely in-register: u1 = ETA*b, a1 = soft(u1) ---
    float uv0 = ETA * bv0;
    float av0 = softt(uv0, lam);

    const size_t aoff0 = (size_t)(rb + l15) * NEU + kbase + q8;  // halves

    publish16(rot, idx0, av0, lane);                 // rot[0]
    setflag(arr, 1u, tid, blockIdx.x);

    for (int step = 1; step < STEPS; ++step) {       // steps 1..98
        const unsigned short* A = rot + (size_t)(step - 1) * SLOT;

        // wait for THIS wave's 16 producers (own half) to publish slot step-1
        {
            const unsigned int* fp = arr + (size_t)(pbase + l15) * 16;
            for (;;) {
                unsigned int v = __hip_atomic_load(fp, __ATOMIC_RELAXED,
                                                   __HIP_MEMORY_SCOPE_AGENT);
                if (__ballot(v < (unsigned int)step) == 0ULL) break;
            }
            // order the A-loads after the poll WITHOUT clobbering all memory:
            // false dependency on the pointer the loads use.
            asm volatile("" : "+s"(A));
        }

        f32x4 acc00 = {}, acc01 = {};
        #pragma unroll
        for (int hb = 0; hb < 2; ++hb) {             // 2 batches of 8 frags
            bf16x8 s0[8];
            #pragma unroll
            for (int f = 0; f < 8; ++f)
                s0[f] = ldfrag_g(A + aoff0 + (hb * 8 + f) * 32);
            #pragma unroll
            for (int f = 0; f < 8; ++f) {
                const int g = hb * 8 + f;
                acc00 = __builtin_amdgcn_mfma_f32_16x16x32_bf16(s0[f], gf[0][g], acc00, 0, 0, 0);
                acc01 = __builtin_amdgcn_mfma_f32_16x16x32_bf16(s0[f], gf[1][g], acc01, 0, 0, 0);
            }
        }
        // stage partials: red[w][ m*32 + nn ],  m = q*4 + r, nn = j*16 + l15
        #pragma unroll
        for (int r = 0; r < 4; ++r) {
            red[w * 512 + (q * 4 + r) * 32 + l15]      = acc00[r];
            red[w * 512 + (q * 4 + r) * 32 + 16 + l15] = acc01[r];
        }
        __syncthreads();
        float s0v = 0.f;
        #pragma unroll
        for (int w8 = 0; w8 < 8; ++w8) s0v += red[w8 * 512 + tid];

        uv0 = fmaf(ETA, bv0 - s0v + av0 - uv0, uv0);
        av0 = softt(uv0, lam);

        if (step == STEPS - 1) {
            aout[idx0] = av0;
        } else {
            publish16(rot + (size_t)step * SLOT, idx0, av0, lane);
            setflag(arr, (unsigned int)(step + 1), tid, blockIdx.x);
        }
    }
}

// ===========================================================================
// Fallback fp32 path (round-1, known correct) for small ws_size
// ===========================================================================
__global__ void lca_init_f(const float* __restrict__ x, const float* __restrict__ phi,
                           float* __restrict__ b, float* __restrict__ u,
                           float* __restrict__ a) {
    const int n  = blockIdx.x * 64 + (threadIdx.x & 63);
    const int bi = blockIdx.y * 4 + (threadIdx.x >> 6);
    const float* xr = x + bi * PIX;
    float acc = 0.f;
    #pragma unroll 4
    for (int p = 0; p < PIX; ++p) acc = fmaf(xr[p], phi[p * NEU + n], acc);
    const int idx = bi * NEU + n;
    b[idx] = acc; u[idx] = 0.f; a[idx] = 0.f;
}
__global__ void lca_s_f(const float* __restrict__ a, const float* __restrict__ phi,
                        float* __restrict__ s) {
    const int lane = threadIdx.x & 63, w = threadIdx.x >> 6;
    const int bi = blockIdx.y, p0 = (blockIdx.x * 4 + w) * 8;
    const float* ar = a + bi * NEU;
    float acc[8] = {};
    for (int i = 0; i < NEU / 64; ++i) {
        const int n = i * 64 + lane;
        const float av = ar[n];
        #pragma unroll
        for (int j = 0; j < 8; ++j) acc[j] = fmaf(av, phi[(p0 + j) * NEU + n], acc[j]);
    }
    float out = 0.f;
    #pragma unroll
    for (int j = 0; j < 8; ++j) {
        float v = acc[j];
        v += __shfl_xor(v, 1, 64); v += __shfl_xor(v, 2, 64); v += __shfl_xor(v, 4, 64);
        v += __shfl_xor(v, 8, 64); v += __shfl_xor(v, 16, 64); v += __shfl_xor(v, 32, 64);
        if (lane == j) out = v;
    }
    if (lane < 8) s[bi * PIX + p0 + lane] = out;
}
__global__ void lca_t_f(const float* __restrict__ s, const float* __restrict__ phi,
                        const float* __restrict__ b, float* __restrict__ u,
                        float* __restrict__ a, const float* __restrict__ lamp) {
    __shared__ float ls[8 * 256];
    const int n = blockIdx.x * 64 + (threadIdx.x & 63);
    const int slot = threadIdx.x >> 6;
    const int bb = blockIdx.y * 8 + slot;
    float acc = 0.f;
    for (int c = 0; c < PIX; c += 256) {
        __syncthreads();
        for (int e = threadIdx.x; e < 8 * 256; e += 512) {
            const int r = e >> 8, p = e & 255;
            ls[e] = s[(blockIdx.y * 8 + r) * PIX + c + p];
        }
        __syncthreads();
        const float* lrow = ls + slot * 256;
        #pragma unroll 8
        for (int p = 0; p < 256; ++p) acc = fmaf(lrow[p], phi[(c + p) * NEU + n], acc);
    }
    const float lam = lamp[0];
    const int idx = bb * NEU + n;
    const float uo = u[idx];
    const float du = b[idx] - acc + a[idx] - uo;
    const float un = fmaf(ETA, du, uo);
    u[idx] = un; a[idx] = softt(un, lam);
}

// ===========================================================================
extern "C" void kernel_launch(void* const* d_in, const int* in_sizes, int n_in,
                              void* d_out, int out_size, void* d_ws, size_t ws_size,
                              hipStream_t stream) {
    const float* x    = (const float*)d_in[0];
    const float* phi  = (const float*)d_in[1];
    const float* lamp = (const float*)d_in[2];
    float* a = (float*)d_out;
    char* ws = (char*)d_ws;

    // rot region (98 x 256 KB) overlays phiT (24 MB): phiT is dead once
    // lca_binit completes, before lca_persist starts.
    const size_t ROT_OFF  = 0;
    const size_t ROT_BYTES= (size_t)(STEPS - 1) * SLOT * 2;         // 25.69 MB
    const size_t PHIT_OFF = 0;                                       // overlay
    const size_t G_OFF    = ROT_OFF + ROT_BYTES;                     // 25.69 MB
    const size_t B_OFF    = G_OFF + (size_t)NEU * NEU * 2;           // +32 MB
    const size_t ARR_OFF  = B_OFF + (size_t)BATCH * NEU * 4;
    const size_t NEED     = ARR_OFF + (size_t)NBLK * 64;             // ~57.0 MB

    if (ws_size >= NEED) {
        unsigned short* phiT = (unsigned short*)(ws + PHIT_OFF);
        unsigned short* rot  = (unsigned short*)(ws + ROT_OFF);
        unsigned short* G    = (unsigned short*)(ws + G_OFF);
        float*          b    = (float*)(ws + B_OFF);
        unsigned int*   arr  = (unsigned int*)(ws + ARR_OFF);

        transp<<<dim3(NEU / 64, PIX / 64), 256, 0, stream>>>(phi, phiT);
        gemm_G<<<dim3(32, 32), 256, 0, stream>>>(phiT, G);
        lca_binit<<<256, 512, 0, stream>>>(x, phiT, b, arr);

        void* args[6];
        const unsigned short* Gc = G;
        const float* bc = b;
        const float* lc = lamp;
        args[0] = (void*)&Gc;
        args[1] = (void*)&bc;
        args[2] = (void*)&rot;
        args[3] = (void*)&a;
        args[4] = (void*)&lc;
        args[5] = (void*)&arr;
        hipLaunchCooperativeKernel((const void*)lca_persist, dim3(NBLK), dim3(TPB),
                                   args, 0, stream);
    } else {
        float* fws = (float*)d_ws;
        float* b = fws;
        float* u = fws + BATCH * NEU;
        float* s = fws + 2 * BATCH * NEU;
        lca_init_f<<<dim3(64, 8), 256, 0, stream>>>(x, phi, b, u, a);
        for (int it = 0; it < STEPS; ++it) {
            lca_s_f<<<dim3(96, 32), 256, 0, stream>>>(a, phi, s);
            lca_t_f<<<dim3(64, 4), 512, 0, stream>>>(s, phi, b, u, a, lamp);
        }
    }
}